// Round 1
// baseline (190.218 us; speedup 1.0000x reference)
//
#include <hip/hip_runtime.h>
#include <math.h>

#define NROWS 4096
#define NHALF 2048
#define DDIM  256
#define INV_T 2.0f   // 1/TEMP, TEMP=0.5

// ---------------------------------------------------------------------------
// Kernel 1: row-normalize (F.normalize semantics: x / max(||x||, eps)).
// Also zero-inits the rowsum/pos accumulators (ws is poisoned 0xAA each call).
// ---------------------------------------------------------------------------
__global__ __launch_bounds__(64) void knorm(const float* __restrict__ xi,
                                            const float* __restrict__ xj,
                                            float* __restrict__ z,
                                            float* __restrict__ rowsum,
                                            float* __restrict__ pos) {
  const int row  = blockIdx.x;
  const int lane = threadIdx.x;           // 64 lanes, 4 floats each = 256
  const float* src = (row < NHALF) ? (xi + (size_t)row * DDIM)
                                   : (xj + (size_t)(row - NHALF) * DDIM);
  float4 v = reinterpret_cast<const float4*>(src)[lane];
  float ss = v.x*v.x + v.y*v.y + v.z*v.z + v.w*v.w;
  #pragma unroll
  for (int off = 1; off < 64; off <<= 1) ss += __shfl_xor(ss, off);
  const float scale = 1.0f / fmaxf(sqrtf(ss), 1e-12f);
  v.x *= scale; v.y *= scale; v.z *= scale; v.w *= scale;
  reinterpret_cast<float4*>(z + (size_t)row * DDIM)[lane] = v;
  if (lane == 0) { rowsum[row] = 0.0f; pos[row] = 0.0f; }
}

// ---------------------------------------------------------------------------
// Kernel 2: fused Z·Z^T + exp + masked row-sum + positive-pair capture.
// Block tile 128(i) x 128(j), micro-tile 8x8 per thread (split 4+4),
// BK=32 K-chunks, LDS tiles stored K-major (transposed) for b128 reads.
// Grid: x = 16 j-splits (256 cols each), y = 32 i-tiles.
// ---------------------------------------------------------------------------
#define BI 128
#define BJ 128
#define BK 32
#define JSPLIT 16
#define JRANGE (NROWS / JSPLIT)   // 256

__global__ __launch_bounds__(256, 2) void ksim(const float* __restrict__ z,
                                               float* __restrict__ rowsum,
                                               float* __restrict__ pos) {
  __shared__ float As[BK][BI + 4];   // +4 pad keeps 16B alignment, spreads banks
  __shared__ float Bs[BK][BJ + 4];
  __shared__ float rs[BI];
  __shared__ float ps[BI];

  const int t  = threadIdx.x;
  const int ti = t & 15;             // i-direction lane in 16x16 thread grid
  const int tj = t >> 4;             // j-direction
  const int i0 = blockIdx.y * BI;
  const int jbase = blockIdx.x * JRANGE;

  float esum[8];
  float posacc[8];
  #pragma unroll
  for (int u = 0; u < 8; ++u) { esum[u] = 0.0f; posacc[u] = 0.0f; }

  const int rl = t >> 3;             // 0..31 : staging row within 32-row pass
  const int c4 = (t & 7) * 4;        // 0..28 : staging col group (float4)

  for (int jt = 0; jt < JRANGE / BJ; ++jt) {   // 2 iterations
    const int j0 = jbase + jt * BJ;
    float acc[8][8];
    #pragma unroll
    for (int u = 0; u < 8; ++u)
      #pragma unroll
      for (int v = 0; v < 8; ++v) acc[u][v] = 0.0f;

    for (int kc = 0; kc < DDIM / BK; ++kc) {   // 8 K-chunks
      __syncthreads();                          // protect prev-iter LDS reads
      #pragma unroll
      for (int p = 0; p < 4; ++p) {
        const int r = rl + p * 32;              // 0..127
        const float4 va = *reinterpret_cast<const float4*>(
            z + (size_t)(i0 + r) * DDIM + kc * BK + c4);
        As[c4 + 0][r] = va.x; As[c4 + 1][r] = va.y;
        As[c4 + 2][r] = va.z; As[c4 + 3][r] = va.w;
        const float4 vb = *reinterpret_cast<const float4*>(
            z + (size_t)(j0 + r) * DDIM + kc * BK + c4);
        Bs[c4 + 0][r] = vb.x; Bs[c4 + 1][r] = vb.y;
        Bs[c4 + 2][r] = vb.z; Bs[c4 + 3][r] = vb.w;
      }
      __syncthreads();

      #pragma unroll
      for (int kk = 0; kk < BK; ++kk) {
        float a[8], b[8];
        *reinterpret_cast<float4*>(&a[0]) =
            *reinterpret_cast<const float4*>(&As[kk][ti * 4]);
        *reinterpret_cast<float4*>(&a[4]) =
            *reinterpret_cast<const float4*>(&As[kk][64 + ti * 4]);
        *reinterpret_cast<float4*>(&b[0]) =
            *reinterpret_cast<const float4*>(&Bs[kk][tj * 4]);
        *reinterpret_cast<float4*>(&b[4]) =
            *reinterpret_cast<const float4*>(&Bs[kk][64 + tj * 4]);
        #pragma unroll
        for (int u = 0; u < 8; ++u)
          #pragma unroll
          for (int v = 0; v < 8; ++v)
            acc[u][v] = fmaf(a[u], b[v], acc[u][v]);
      }
    }

    // Epilogue for this j-tile: exp, mask diagonal, capture positive pair.
    #pragma unroll
    for (int u = 0; u < 8; ++u) {
      const int ig   = i0 + (u >> 2) * 64 + ti * 4 + (u & 3);
      const int ipos = (ig + NHALF) & (NROWS - 1);
      #pragma unroll
      for (int v = 0; v < 8; ++v) {
        const int jg = j0 + (v >> 2) * 64 + tj * 4 + (v & 3);
        const float s = acc[u][v];
        const float e = __expf(s * INV_T);
        esum[u]   += (jg != ig)   ? e : 0.0f;   // neg_mask: exclude self
        posacc[u] += (jg == ipos) ? s : 0.0f;   // unique owner of positive
      }
    }
  }

  // Block-level per-row reduction, then global atomic accumulate.
  if (t < BI) { rs[t] = 0.0f; ps[t] = 0.0f; }
  __syncthreads();
  #pragma unroll
  for (int u = 0; u < 8; ++u) {
    const int il = (u >> 2) * 64 + ti * 4 + (u & 3);
    atomicAdd(&rs[il], esum[u]);
    atomicAdd(&ps[il], posacc[u]);
  }
  __syncthreads();
  if (t < BI) {
    atomicAdd(&rowsum[i0 + t], rs[t]);
    atomicAdd(&pos[i0 + t], ps[t]);
  }
}

// ---------------------------------------------------------------------------
// Kernel 3: loss_i = log(denom_i) - pos_i/T ; out = mean over 2N rows.
// ---------------------------------------------------------------------------
__global__ __launch_bounds__(1024) void kfinal(const float* __restrict__ rowsum,
                                               const float* __restrict__ pos,
                                               float* __restrict__ out) {
  __shared__ float red[16];
  const int t = threadIdx.x;
  float acc = 0.0f;
  for (int i = t; i < NROWS; i += 1024)
    acc += logf(rowsum[i]) - INV_T * pos[i];
  #pragma unroll
  for (int off = 32; off > 0; off >>= 1) acc += __shfl_down(acc, off);
  if ((t & 63) == 0) red[t >> 6] = acc;
  __syncthreads();
  if (t < 64) {
    float v = (t < 16) ? red[t] : 0.0f;
    #pragma unroll
    for (int off = 8; off > 0; off >>= 1) v += __shfl_down(v, off);
    if (t == 0) out[0] = v * (1.0f / NROWS);
  }
}

// ---------------------------------------------------------------------------
extern "C" void kernel_launch(void* const* d_in, const int* in_sizes, int n_in,
                              void* d_out, int out_size, void* d_ws, size_t ws_size,
                              hipStream_t stream) {
  const float* xi = (const float*)d_in[0];
  const float* xj = (const float*)d_in[1];
  float* out = (float*)d_out;

  float* z      = (float*)d_ws;                 // [4096][256] f32 = 4 MB
  float* rowsum = z + (size_t)NROWS * DDIM;     // [4096]
  float* pos    = rowsum + NROWS;               // [4096]

  knorm<<<NROWS, 64, 0, stream>>>(xi, xj, z, rowsum, pos);
  dim3 grid(JSPLIT, NROWS / BI);                // 16 x 32 = 512 blocks
  ksim<<<grid, 256, 0, stream>>>(z, rowsum, pos);
  kfinal<<<1, 1024, 0, stream>>>(rowsum, pos, out);
}

// Round 5
// 80.997 us; speedup vs baseline: 2.3485x; 2.3485x over previous
//
#include <hip/hip_runtime.h>
#include <math.h>

#define NROWS 4096
#define NHALF 2048
#define DDIM  256
#define INV_T 2.0f   // 1/TEMP, TEMP=0.5

typedef __attribute__((ext_vector_type(8))) __bf16 bf16x8;
typedef __attribute__((ext_vector_type(4))) float  f32x4;

__device__ __forceinline__ unsigned short f2bf(float f) {
  unsigned u = __float_as_uint(f);
  u += 0x7FFF + ((u >> 16) & 1);          // round-to-nearest-even
  return (unsigned short)(u >> 16);
}

__device__ __forceinline__ void gload_lds16(const void* g, void* lds) {
  __builtin_amdgcn_global_load_lds(
      (const __attribute__((address_space(1))) void*)g,
      (__attribute__((address_space(3))) void*)lds, 16, 0, 0);
}

// ---------------------------------------------------------------------------
// Kernel 1: row-normalize in fp32, emit bf16 rows; zero accumulators.
// ---------------------------------------------------------------------------
__global__ __launch_bounds__(64) void knorm(const float* __restrict__ xi,
                                            const float* __restrict__ xj,
                                            unsigned short* __restrict__ z,
                                            float* __restrict__ rowsum,
                                            float* __restrict__ pos) {
  const int row  = blockIdx.x;
  const int lane = threadIdx.x;            // 64 lanes x float4 = 256
  const float* src = (row < NHALF) ? (xi + (size_t)row * DDIM)
                                   : (xj + (size_t)(row - NHALF) * DDIM);
  float4 v = reinterpret_cast<const float4*>(src)[lane];
  float ss = v.x*v.x + v.y*v.y + v.z*v.z + v.w*v.w;
  #pragma unroll
  for (int off = 1; off < 64; off <<= 1) ss += __shfl_xor(ss, off);
  const float scale = 1.0f / fmaxf(sqrtf(ss), 1e-12f);
  ushort4 o;
  o.x = f2bf(v.x * scale); o.y = f2bf(v.y * scale);
  o.z = f2bf(v.z * scale); o.w = f2bf(v.w * scale);
  reinterpret_cast<ushort4*>(z + (size_t)row * DDIM)[lane] = o;
  if (lane == 0) { rowsum[row] = 0.0f; pos[row] = 0.0f; }
}

// ---------------------------------------------------------------------------
// Kernel 2: bf16 MFMA Gram tile 128x128 + fused exp / mask / row-sum / pos.
// 4 waves (2x2), each 64x64 = 4x4 frags of 16x16x32. BK=64 per stage.
// LDS rows are 128B (64 bf16); 16B-chunk XOR swizzle (chunk ^= row&7):
// linear global_load_lds dest + inverse-swizzled global src + swizzled read.
// ---------------------------------------------------------------------------
__global__ __launch_bounds__(256, 4) void ksim(const unsigned short* __restrict__ z,
                                               float* __restrict__ rowsum,
                                               float* __restrict__ pos) {
  __shared__ __align__(16) unsigned short As[128 * 64];   // 16 KB
  __shared__ __align__(16) unsigned short Bs[128 * 64];   // 16 KB

  const int t  = threadIdx.x;
  const int w  = t >> 6;                  // wave 0..3
  const int l  = t & 63;
  const int wm = w >> 1, wn = w & 1;      // 2x2 wave grid
  const int i0 = blockIdx.y * 128;
  const int j0 = blockIdx.x * 128;

  const char* zb = (const char*)z;        // row stride 512 B
  char* Ab = (char*)As;
  char* Bb = (char*)Bs;

  // staging lane constants: one inst = 8 rows x 128B; lane l -> row l>>3,
  // lds chunk l&7; global src chunk = (l&7) ^ (row&7) = (l&7) ^ (l>>3)
  const int srow   = l >> 3;
  const int schunk = ((l & 7) ^ (l >> 3)) * 16;

  const int li = l & 15;                  // frag col lane
  const int g  = l >> 4;                  // k-group 0..3
  const int sw = l & 7;                   // row&7 for all frag rows

  f32x4 acc[4][4];
  #pragma unroll
  for (int m = 0; m < 4; ++m)
    #pragma unroll
    for (int n = 0; n < 4; ++n) acc[m][n] = (f32x4)0.0f;

  for (int kc = 0; kc < 4; ++kc) {        // K = 4 x 64
    __syncthreads();                      // prev-iter LDS reads done
    #pragma unroll
    for (int p = 0; p < 4; ++p) {
      const int r0 = w * 32 + p * 8;      // this wave's 8-row slab
      gload_lds16(zb + (size_t)(i0 + r0 + srow) * 512 + kc * 128 + schunk,
                  Ab + r0 * 128);
      gload_lds16(zb + (size_t)(j0 + r0 + srow) * 512 + kc * 128 + schunk,
                  Bb + r0 * 128);
    }
    __syncthreads();                      // drains vmcnt (global_load_lds)

    #pragma unroll
    for (int s = 0; s < 2; ++s) {         // two K=32 slices per stage
      const int coff = (((s * 4 + g) ^ sw) * 16);
      bf16x8 af[4], bfr[4];
      #pragma unroll
      for (int m = 0; m < 4; ++m)
        af[m] = *(const bf16x8*)(Ab + (wm * 64 + m * 16 + li) * 128 + coff);
      #pragma unroll
      for (int n = 0; n < 4; ++n)
        bfr[n] = *(const bf16x8*)(Bb + (wn * 64 + n * 16 + li) * 128 + coff);
      #pragma unroll
      for (int m = 0; m < 4; ++m)
        #pragma unroll
        for (int n = 0; n < 4; ++n)
          acc[m][n] = __builtin_amdgcn_mfma_f32_16x16x32_bf16(
              af[m], bfr[n], acc[m][n], 0, 0, 0);
    }
  }

  // Epilogue: C/D map col=lane&15, row=(lane>>4)*4+reg. exp, mask, reduce.
  #pragma unroll
  for (int m = 0; m < 4; ++m) {
    #pragma unroll
    for (int r = 0; r < 4; ++r) {
      const int ig   = i0 + wm * 64 + m * 16 + g * 4 + r;
      const int ipos = (ig + NHALF) & (NROWS - 1);
      float es = 0.0f, ps = 0.0f;
      #pragma unroll
      for (int n = 0; n < 4; ++n) {
        const int jg = j0 + wn * 64 + n * 16 + li;
        const float sv = acc[m][n][r];
        const float e  = __expf(sv * INV_T);
        es += (jg != ig)   ? e  : 0.0f;   // exclude self
        ps += (jg == ipos) ? sv : 0.0f;   // unique positive owner
      }
      #pragma unroll
      for (int off = 1; off < 16; off <<= 1) {
        es += __shfl_xor(es, off);
        ps += __shfl_xor(ps, off);
      }
      if (li == 0) {
        atomicAdd(&rowsum[ig], es);
        atomicAdd(&pos[ig], ps);
      }
    }
  }
}

// ---------------------------------------------------------------------------
// Kernel 3: loss_i = log(denom_i) - pos_i/T ; out = mean.
// ---------------------------------------------------------------------------
__global__ __launch_bounds__(1024) void kfinal(const float* __restrict__ rowsum,
                                               const float* __restrict__ pos,
                                               float* __restrict__ out) {
  __shared__ float red[16];
  const int t = threadIdx.x;
  float acc = 0.0f;
  for (int i = t; i < NROWS; i += 1024)
    acc += logf(rowsum[i]) - INV_T * pos[i];
  #pragma unroll
  for (int off = 32; off > 0; off >>= 1) acc += __shfl_down(acc, off);
  if ((t & 63) == 0) red[t >> 6] = acc;
  __syncthreads();
  if (t < 64) {
    float v = (t < 16) ? red[t] : 0.0f;
    #pragma unroll
    for (int off = 8; off > 0; off >>= 1) v += __shfl_down(v, off);
    if (t == 0) out[0] = v * (1.0f / NROWS);
  }
}

// ---------------------------------------------------------------------------
extern "C" void kernel_launch(void* const* d_in, const int* in_sizes, int n_in,
                              void* d_out, int out_size, void* d_ws, size_t ws_size,
                              hipStream_t stream) {
  const float* xi = (const float*)d_in[0];
  const float* xj = (const float*)d_in[1];
  float* out = (float*)d_out;

  unsigned short* z = (unsigned short*)d_ws;                 // [4096][256] bf16 = 2 MB
  float* rowsum = (float*)((char*)d_ws + (size_t)NROWS * DDIM * 2);
  float* pos    = rowsum + NROWS;

  knorm<<<NROWS, 64, 0, stream>>>(xi, xj, z, rowsum, pos);
  dim3 grid(NROWS / 128, NROWS / 128);                       // 32 x 32
  ksim<<<grid, 256, 0, stream>>>(z, rowsum, pos);
  kfinal<<<1, 1024, 0, stream>>>(rowsum, pos, out);
}